// Round 1
// 16993.304 us; speedup vs baseline: 1.3897x; 1.3897x over previous
//
#include <hip/hip_runtime.h>
#include <math.h>
#include <stdint.h>

#define TB 256    // T time steps
#define NB 32     // batch
#define EV 10000  // vocab
#define ED 256    // embed dim
#define HD 512    // hidden
#define NM 128    // memory slots
#define WDIM 64   // word dim
#define RH 4      // read heads
#define NIF 471   // interface size
#define CEPS 1e-6f

__device__ __forceinline__ float sigm(float x) { return 1.0f / (1.0f + expf(-x)); }
// jax.nn.softplus = logaddexp(x,0), numerically stable form:
__device__ __forceinline__ float sofp(float x) { return fmaxf(x, 0.0f) + log1pf(expf(-fabsf(x))); }

// reductions over values held by threads 0..127; ALL threads must call.
__device__ __forceinline__ float red128_max(float v, int tid, float* red2) {
#pragma unroll
  for (int m = 32; m > 0; m >>= 1) v = fmaxf(v, __shfl_xor(v, m));
  if (tid == 0) red2[0] = v;
  if (tid == 64) red2[1] = v;
  __syncthreads();
  float r = fmaxf(red2[0], red2[1]);
  __syncthreads();
  return r;
}
__device__ __forceinline__ float red128_sum(float v, int tid, float* red2) {
#pragma unroll
  for (int m = 32; m > 0; m >>= 1) v += __shfl_xor(v, m);
  if (tid == 0) red2[0] = v;
  if (tid == 64) red2[1] = v;
  __syncthreads();
  float r = red2[0] + red2[1];
  __syncthreads();
  return r;
}

// ---------------------------------------------------------------- embedding
__global__ __launch_bounds__(256) void k_embed(const int* __restrict__ tok,
                                               const float* __restrict__ emb,
                                               float* __restrict__ x) {
  int gid = blockIdx.x * 256 + threadIdx.x;  // < B*T*E = 2097152
  int bt = gid >> 8, k = gid & 255;
  int t = tok[bt];
  x[gid] = tanhf(emb[(size_t)t * ED + k]);
}

// ------------------------------------------------- LSTM gates + cell update
// Block bk computes units [2*bk, 2*bk+2) x 4 gates for all 32 batches.
__global__ __launch_bounds__(256) void k_gates(
    const float* __restrict__ xall, const float* __restrict__ rv,
    const float* __restrict__ h0, float* __restrict__ c,
    const float* __restrict__ wih, const float* __restrict__ whh,
    const float* __restrict__ blstm, float* __restrict__ hrv, int step) {
  __shared__ float U[NB][257];  // [batch][k-tile], +1 pad -> conflict-free reads
  __shared__ float G[8][NB];
  const int tid = threadIdx.x;
  const int b = tid & 31, jj = tid >> 5;  // jj = ul*4 + g
  const int ul = jj >> 2, g = jj & 3;
  const int u0 = blockIdx.x * 2;
  const int j = (u0 + ul) + (g << 9);  // gate row in [0,2048)
  float a0 = blstm[j], a1 = 0.f, a2 = 0.f, a3 = 0.f;
  const float* wbase = wih + (size_t)j * 512;
  const float* wbase2 = whh + (size_t)j * 512;
  for (int tile = 0; tile < 4; ++tile) {
    // cooperative fill of U[bb][0..255] (coalesced: 64 lanes cover one b-row)
#pragma unroll
    for (int i = 0; i < 8; ++i) {
      int f = tid + (i << 8);
      int bb = f >> 6, k = (f & 63) << 2;
      const float* src;
      if (tile == 0)
        src = xall + (((size_t)bb * TB + step) << 8) + k;
      else if (tile == 1)
        src = rv + (bb << 8) + k;
      else {
        const float* hp = step ? (hrv + ((size_t)bb * TB + step - 1) * 768)
                               : (h0 + (bb << 9));
        src = hp + ((tile - 2) << 8) + k;
      }
      float4 v = *reinterpret_cast<const float4*>(src);
      U[bb][k] = v.x; U[bb][k + 1] = v.y; U[bb][k + 2] = v.z; U[bb][k + 3] = v.w;
    }
    __syncthreads();
    const float4* wp = reinterpret_cast<const float4*>(
        (tile < 2 ? wbase : wbase2) + ((tile & 1) << 8));
#pragma unroll 4
    for (int k4 = 0; k4 < 64; ++k4) {
      float4 w4 = wp[k4];
      int k = k4 << 2;
      a0 = fmaf(U[b][k], w4.x, a0);
      a1 = fmaf(U[b][k + 1], w4.y, a1);
      a2 = fmaf(U[b][k + 2], w4.z, a2);
      a3 = fmaf(U[b][k + 3], w4.w, a3);
    }
    __syncthreads();
  }
  G[jj][b] = (a0 + a1) + (a2 + a3);
  __syncthreads();
  if (tid < 64) {
    int u2 = tid >> 5, bb = tid & 31;
    int u = u0 + u2;
    float gi = G[u2 * 4 + 0][bb], gf = G[u2 * 4 + 1][bb];
    float gg = G[u2 * 4 + 2][bb], go = G[u2 * 4 + 3][bb];
    float cold = c[(bb << 9) + u];
    float cn = sigm(gf) * cold + sigm(gi) * tanhf(gg);
    float hn = sigm(go) * tanhf(cn);
    c[(bb << 9) + u] = cn;
    hrv[((size_t)bb * TB + step) * 768 + u] = hn;
  }
}

// --------------------------------------- interface matvec + DNC memory step
// One block of 1024 threads (16 waves -> 4 waves/SIMD for latency hiding)
// per batch. M cached in LDS; L operated in global (L2-resident).
__global__ __launch_bounds__(1024) void k_mem(
    float* __restrict__ hrv, const float* __restrict__ wif,
    const float* __restrict__ bif, float* __restrict__ M_g,
    float* __restrict__ L_g, float* __restrict__ p_g, float* __restrict__ u_g,
    float* __restrict__ wr_g, float* __restrict__ ww_g,
    float* __restrict__ rv_g, int step) {
  __shared__ float h_s[512];
  __shared__ float xi_s[472];
  __shared__ float xip_s[512][2];    // xi partial sums (2 k-halves)
  __shared__ float M_s[NM][65];      // +1 pad
  __shared__ float wro_s[4][NM];
  __shared__ float fwd_s[4][NM];
  __shared__ float bwd_s[4][NM];
  __shared__ float crsd_s[4][NM];    // raw read-key dots vs new M
  __shared__ float wrn_s[4][NM];
  __shared__ float un_s[NM];
  __shared__ float wwn_s[NM];
  __shared__ float po_s[NM];
  __shared__ float nrmp_s[NM][8];    // |M_new row|^2 partials from B3
  __shared__ float nrm_s[NM];
  __shared__ float er_s[WDIM];
  __shared__ float wv_s[WDIM];
  __shared__ float rvp_s[256][5];    // rv partials (+pad)
  __shared__ float rb_s[4], fg_s[4], rkn_s[4];
  __shared__ float pi_s[12];
  __shared__ float red2[2];
  __shared__ float redw[8];
  __shared__ float hm_s[4], hs_s[4];
  __shared__ float sc_s[4];  // 0: wb, 1: ga, 2: gw, 3: |wk|

  const int tid = threadIdx.x;
  const int b = blockIdx.x;
  const size_t row = (size_t)b * TB + step;
  float* hp = hrv + row * 768;
  float* Mg = M_g + (size_t)b * (NM * WDIM);
  float* Lg = L_g + (size_t)b * (NM * NM);

  // ---- phase A: fills
  if (tid < 512) h_s[tid] = hp[tid];
  for (int f = tid; f < 2048; f += 1024) {
    float4 v = reinterpret_cast<const float4*>(Mg)[f];
    int n = f >> 4, w = (f & 15) << 2;
    M_s[n][w] = v.x; M_s[n][w + 1] = v.y; M_s[n][w + 2] = v.z; M_s[n][w + 3] = v.w;
  }
  if (tid < 512) wro_s[tid >> 7][tid & 127] = wr_g[b * 512 + tid];
  float uo = 0.f, wwo = 0.f;
  if (tid < 128) {
    uo = u_g[b * 128 + tid];
    wwo = ww_g[b * 128 + tid];
    po_s[tid] = p_g[b * 128 + tid];
  }
  __syncthreads();

  // ---- interface vector xi = h @ W_iface + b_iface ; 2 threads per column
  {
    int half = tid >> 9, c = tid & 511;
    if (c < NIF) {
      const float* wp = wif + (size_t)(half * 256) * NIF + c;
      const float* hh = h_s + half * 256;
      float a0 = 0.f, a1 = 0.f, a2 = 0.f, a3 = 0.f;
      for (int k = 0; k < 256; k += 4) {
        a0 = fmaf(hh[k + 0], wp[(size_t)(k + 0) * NIF], a0);
        a1 = fmaf(hh[k + 1], wp[(size_t)(k + 1) * NIF], a1);
        a2 = fmaf(hh[k + 2], wp[(size_t)(k + 2) * NIF], a2);
        a3 = fmaf(hh[k + 3], wp[(size_t)(k + 3) * NIF], a3);
      }
      xip_s[c][half] = (a0 + a1) + (a2 + a3);
    }
  }
  __syncthreads();
  if (tid < NIF) xi_s[tid] = bif[tid] + xip_s[tid][0] + xip_s[tid][1];
  __syncthreads();

  // ---- parse interface
  if (tid < 64) {
    er_s[tid] = sigm(xi_s[325 + tid]);
    wv_s[tid] = xi_s[389 + tid];
  } else if (tid < 68) {
    rb_s[tid - 64] = 1.0f + sofp(xi_s[256 + (tid - 64)]);
  } else if (tid < 72) {
    fg_s[tid - 68] = sigm(xi_s[453 + (tid - 68)]);
  } else if (tid < 76) {
    int r = tid - 72;
    float nq = 0.f;
    for (int w = 0; w < 64; ++w) { float v = xi_s[r * 64 + w]; nq = fmaf(v, v, nq); }
    rkn_s[r] = sqrtf(nq);
  } else if (tid < 80) {
    int r = tid - 76;
    float e0 = xi_s[459 + 3 * r], e1 = xi_s[460 + 3 * r], e2 = xi_s[461 + 3 * r];
    float mx = fmaxf(e0, fmaxf(e1, e2));
    float p0 = expf(e0 - mx), p1 = expf(e1 - mx), p2 = expf(e2 - mx);
    float s = p0 + p1 + p2;
    pi_s[3 * r] = p0 / s; pi_s[3 * r + 1] = p1 / s; pi_s[3 * r + 2] = p2 / s;
  } else if (tid == 80) {
    sc_s[0] = 1.0f + sofp(xi_s[324]);
  } else if (tid == 81) {
    sc_s[1] = sigm(xi_s[457]);
  } else if (tid == 82) {
    sc_s[2] = sigm(xi_s[458]);
  } else if (tid == 83) {
    float nq = 0.f;
    for (int w = 0; w < 64; ++w) { float v = xi_s[260 + w]; nq = fmaf(v, v, nq); }
    sc_s[3] = sqrtf(nq);
  }
  __syncthreads();

  // ---- B1: retention/usage + content-write scores (old M)
  float score = -1e30f;
  if (tid < 128) {
    int n = tid;
    float psi = 1.0f;
#pragma unroll
    for (int r = 0; r < 4; ++r) psi *= (1.0f - fg_s[r] * wro_s[r][n]);
    float un = (uo + wwo - uo * wwo) * psi;
    un_s[n] = un;
    u_g[b * 128 + n] = un;
    float d0 = 0.f, d1 = 0.f, q0 = 0.f, q1 = 0.f;
#pragma unroll 4
    for (int w = 0; w < 64; w += 2) {
      float m0 = M_s[n][w], m1 = M_s[n][w + 1];
      d0 = fmaf(m0, xi_s[260 + w], d0); q0 = fmaf(m0, m0, q0);
      d1 = fmaf(m1, xi_s[260 + w + 1], d1); q1 = fmaf(m1, m1, q1);
    }
    score = sc_s[0] * (d0 + d1) / (sc_s[3] * sqrtf(q0 + q1) + CEPS);
  }
  __syncthreads();

  // ---- B2: allocation (stable-order O(N^2) product == stable argsort+cumprod)
  float aval = 0.f;
  if (tid < 128) {
    int n = tid;
    float un = un_s[n];
    float p0 = 1.0f, p1 = 1.0f;
#pragma unroll 4
    for (int m = 0; m < 128; m += 2) {
      float u0 = un_s[m], u1 = un_s[m + 1];
      p0 *= ((u0 < un) || (u0 == un && m < n)) ? u0 : 1.0f;
      p1 *= ((u1 < un) || (u1 == un && (m + 1) < n)) ? u1 : 1.0f;
    }
    aval = (1.0f - un) * p0 * p1;
  }
  float gmax = red128_max(score, tid, red2);
  float ev = (tid < 128) ? expf(score - gmax) : 0.f;
  float gsum = red128_sum(ev, tid, red2);
  float wwv = 0.f;
  if (tid < 128) {
    float cw = ev / gsum;
    wwv = sc_s[2] * (sc_s[1] * aval + (1.0f - sc_s[1]) * cw);
    wwn_s[tid] = wwv;
    ww_g[b * 128 + tid] = wwv;
  }
  float sumww = red128_sum(wwv, tid, red2);  // syncs make wwn_s visible

  // ---- B3: M update (LDS+global, +norm partials), L update (global), p update
  {
    int n = tid >> 3, w0 = (tid & 7) << 3;
    float wn = wwn_s[n];
    float nq = 0.f;
    float mv_[8];
#pragma unroll
    for (int j = 0; j < 8; ++j) {
      int w = w0 + j;
      float mv = M_s[n][w];
      mv = mv * (1.0f - wn * er_s[w]) + wn * wv_s[w];
      M_s[n][w] = mv;
      mv_[j] = mv;
      nq = fmaf(mv, mv, nq);
    }
    nrmp_s[n][tid & 7] = nq;
    float4* mg4 = reinterpret_cast<float4*>(Mg + (n << 6) + w0);
    mg4[0] = make_float4(mv_[0], mv_[1], mv_[2], mv_[3]);
    mg4[1] = make_float4(mv_[4], mv_[5], mv_[6], mv_[7]);
  }
  for (int e = tid; e < NM * NM; e += 1024) {
    int n = e >> 7, m = e & 127;
    float lv = Lg[e];
    float nv = (n == m) ? 0.f
                        : (1.0f - wwn_s[n] - wwn_s[m]) * lv + wwn_s[n] * po_s[m];
    Lg[e] = nv;
  }
  if (tid < 128) p_g[b * 128 + tid] = (1.0f - sumww) * po_s[tid] + wwn_s[tid];
  __syncthreads();

  // ---- B4: 1024 fwd/bwd dots (new L, old wr) + norm reduce + cr raw dots
  {
    int type = tid >> 9, r = (tid >> 7) & 3, n = tid & 127;
    const float* wrr = wro_s[r];
    float a0 = 0.f, a1 = 0.f, a2 = 0.f, a3 = 0.f;
    if (type == 0) {  // fwd[r][n] = sum_m L[n][m] * wr[r][m]
      const float* Lr = Lg + (n << 7);
#pragma unroll 4
      for (int m = 0; m < 128; m += 4) {
        float4 l4 = *reinterpret_cast<const float4*>(Lr + m);
        a0 = fmaf(l4.x, wrr[m + 0], a0);
        a1 = fmaf(l4.y, wrr[m + 1], a1);
        a2 = fmaf(l4.z, wrr[m + 2], a2);
        a3 = fmaf(l4.w, wrr[m + 3], a3);
      }
      fwd_s[r][n] = (a0 + a1) + (a2 + a3);
    } else {  // bwd[r][n] = sum_m L[m][n] * wr[r][m]  (coalesced across lanes)
      const float* Lc = Lg + n;
#pragma unroll 4
      for (int m = 0; m < 128; m += 4) {
        a0 = fmaf(Lc[(m + 0) << 7], wrr[m + 0], a0);
        a1 = fmaf(Lc[(m + 1) << 7], wrr[m + 1], a1);
        a2 = fmaf(Lc[(m + 2) << 7], wrr[m + 2], a2);
        a3 = fmaf(Lc[(m + 3) << 7], wrr[m + 3], a3);
      }
      bwd_s[r][n] = (a0 + a1) + (a2 + a3);
    }
  }
  if (tid < 128) {
    float s = 0.f;
#pragma unroll
    for (int j = 0; j < 8; ++j) s += nrmp_s[tid][j];
    nrm_s[tid] = sqrtf(s);
  }
  if (tid < 512) {  // raw read-key dots vs new M
    int r = tid >> 7, n = tid & 127;
    const float* xk = xi_s + r * 64;
    float d0 = 0.f, d1 = 0.f, d2 = 0.f, d3 = 0.f;
#pragma unroll 4
    for (int w = 0; w < 64; w += 4) {
      d0 = fmaf(M_s[n][w + 0], xk[w + 0], d0);
      d1 = fmaf(M_s[n][w + 1], xk[w + 1], d1);
      d2 = fmaf(M_s[n][w + 2], xk[w + 2], d2);
      d3 = fmaf(M_s[n][w + 3], xk[w + 3], d3);
    }
    crsd_s[r][n] = (d0 + d1) + (d2 + d3);
  }
  __syncthreads();

  // ---- B5: batched 4-head softmax over slots, then read weights
  {
    int r = (tid >> 7) & 3, n = tid & 127;
    float v = -1e30f;
    if (tid < 512) v = rb_s[r] * crsd_s[r][n] / (rkn_s[r] * nrm_s[n] + CEPS);
    float mx = v;
#pragma unroll
    for (int m = 32; m > 0; m >>= 1) mx = fmaxf(mx, __shfl_xor(mx, m));
    if ((tid & 63) == 0 && tid < 512) redw[tid >> 6] = mx;
    __syncthreads();
    if (tid < 4) hm_s[tid] = fmaxf(redw[2 * tid], redw[2 * tid + 1]);
    __syncthreads();
    float e = 0.f;
    if (tid < 512) e = expf(v - hm_s[r]);
    float sm = e;
#pragma unroll
    for (int m = 32; m > 0; m >>= 1) sm += __shfl_xor(sm, m);
    if ((tid & 63) == 0 && tid < 512) redw[tid >> 6] = sm;
    __syncthreads();
    if (tid < 4) hs_s[tid] = redw[2 * tid] + redw[2 * tid + 1];
    __syncthreads();
    if (tid < 512) {
      float crn = e / hs_s[r];
      float w = pi_s[3 * r] * bwd_s[r][n] + pi_s[3 * r + 1] * crn +
                pi_s[3 * r + 2] * fwd_s[r][n];
      wrn_s[r][n] = w;
      wr_g[b * 512 + r * 128 + n] = w;
    }
  }
  __syncthreads();

  // ---- B6: read vectors rv = wr_new @ M_new ; 4 threads per output
  {
    int out = tid & 255, q = tid >> 8;
    int r = out >> 6, w = out & 63;
    const float* wrr = wrn_s[r];
    int n0 = q << 5;
    float a0 = 0.f, a1 = 0.f;
#pragma unroll 4
    for (int n = n0; n < n0 + 32; n += 2) {
      a0 = fmaf(wrr[n], M_s[n][w], a0);
      a1 = fmaf(wrr[n + 1], M_s[n + 1][w], a1);
    }
    rvp_s[out][q] = a0 + a1;
  }
  __syncthreads();
  if (tid < 256) {
    float acc = rvp_s[tid][0] + rvp_s[tid][1] + rvp_s[tid][2] + rvp_s[tid][3];
    rv_g[b * 256 + tid] = acc;
    hp[512 + tid] = acc;
  }
}

// ---------------------------------------------- deferred output projection
// C(8192x10000) = A(8192x768) @ W(768x10000) + bias ; fp32, 128x128x8 tiles.
__global__ __launch_bounds__(256) void k_out(const float* __restrict__ A,
                                             const float* __restrict__ W,
                                             const float* __restrict__ bias,
                                             float* __restrict__ C) {
  __shared__ float As[8][128];
  __shared__ float Bs[8][128];
  const int tid = threadIdx.x;
  const int tx = tid & 15, ty = tid >> 4;
  const int m0 = blockIdx.x << 7;
  const int n0 = blockIdx.y << 7;
  float acc[8][8];
#pragma unroll
  for (int i = 0; i < 8; ++i)
#pragma unroll
    for (int j = 0; j < 8; ++j) acc[i][j] = 0.f;
  const int arow = tid >> 1, akk = (tid & 1) << 2;
  const int bk = tid >> 5, bn = (tid & 31) << 2;
  for (int k0 = 0; k0 < 768; k0 += 8) {
    float4 av = *reinterpret_cast<const float4*>(A + (size_t)(m0 + arow) * 768 + k0 + akk);
    float4 bv = make_float4(0.f, 0.f, 0.f, 0.f);
    if (n0 + bn < EV)
      bv = *reinterpret_cast<const float4*>(W + (size_t)(k0 + bk) * EV + n0 + bn);
    __syncthreads();  // previous iteration's reads complete
    As[akk + 0][arow] = av.x; As[akk + 1][arow] = av.y;
    As[akk + 2][arow] = av.z; As[akk + 3][arow] = av.w;
    *reinterpret_cast<float4*>(&Bs[bk][bn]) = bv;
    __syncthreads();
#pragma unroll
    for (int k = 0; k < 8; ++k) {
      float a_[8], b_[8];
#pragma unroll
      for (int i = 0; i < 8; ++i) a_[i] = As[k][ty + (i << 4)];
#pragma unroll
      for (int j = 0; j < 8; ++j) b_[j] = Bs[k][tx + (j << 4)];
#pragma unroll
      for (int i = 0; i < 8; ++i)
#pragma unroll
        for (int j = 0; j < 8; ++j) acc[i][j] = fmaf(a_[i], b_[j], acc[i][j]);
    }
  }
#pragma unroll
  for (int i = 0; i < 8; ++i) {
    int row = m0 + ty + (i << 4);
#pragma unroll
    for (int j = 0; j < 8; ++j) {
      int col = n0 + tx + (j << 4);
      if (col < EV) C[(size_t)row * EV + col] = acc[i][j] + bias[col];
    }
  }
}

extern "C" void kernel_launch(void* const* d_in, const int* in_sizes, int n_in,
                              void* d_out, int out_size, void* d_ws,
                              size_t ws_size, hipStream_t stream) {
  const int* tokens = (const int*)d_in[0];
  const float* emb = (const float*)d_in[1];
  const float* wih = (const float*)d_in[2];
  const float* whh = (const float*)d_in[3];
  const float* blstm = (const float*)d_in[4];
  const float* wif = (const float*)d_in[5];
  const float* bif = (const float*)d_in[6];
  const float* wout = (const float*)d_in[7];
  const float* bout = (const float*)d_in[8];
  float* out = (float*)d_out;

  float* ws = (float*)d_ws;
  float* xall = ws;                    // 2,097,152
  float* hrv = xall + 2097152;         // 6,291,456  (B*T x [h(512)|rv(256)])
  float* h0 = hrv + 6291456;           // state block start (zeroed)
  float* cS = h0 + 16384;
  float* MS = cS + 16384;
  float* LS = MS + 262144;
  float* pS = LS + 524288;
  float* uS = pS + 4096;
  float* wrS = uS + 4096;
  float* wwS = wrS + 16384;
  float* rvS = wwS + 4096;             // ends at h0 + 856064

  hipMemsetAsync(h0, 0, (size_t)856064 * sizeof(float), stream);
  k_embed<<<8192, 256, 0, stream>>>(tokens, emb, xall);
  for (int t = 0; t < TB; ++t) {
    k_gates<<<256, 256, 0, stream>>>(xall, rvS, h0, cS, wih, whh, blstm, hrv, t);
    k_mem<<<32, 1024, 0, stream>>>(hrv, wif, bif, MS, LS, pS, uS, wrS, wwS, rvS, t);
  }
  dim3 g(64, 79);
  k_out<<<g, 256, 0, stream>>>(hrv, wout, bout, out);
}

// Round 2
// 15532.326 us; speedup vs baseline: 1.5204x; 1.0941x over previous
//
#include <hip/hip_runtime.h>
#include <math.h>
#include <stdint.h>

#define TB 256    // T time steps
#define NB 32     // batch
#define EV 10000  // vocab
#define ED 256    // embed dim
#define HD 512    // hidden
#define NM 128    // memory slots
#define WDIM 64   // word dim
#define RH 4      // read heads
#define NIF 471   // interface size
#define NIFP 480  // padded row stride for xi
#define CEPS 1e-6f

__device__ __forceinline__ float sigm(float x) { return 1.0f / (1.0f + expf(-x)); }
__device__ __forceinline__ float sofp(float x) { return fmaxf(x, 0.0f) + log1pf(expf(-fabsf(x))); }

// reductions over values held by threads 0..127; ALL threads must call.
__device__ __forceinline__ float red128_max(float v, int tid, float* red2) {
#pragma unroll
  for (int m = 32; m > 0; m >>= 1) v = fmaxf(v, __shfl_xor(v, m));
  if (tid == 0) red2[0] = v;
  if (tid == 64) red2[1] = v;
  __syncthreads();
  float r = fmaxf(red2[0], red2[1]);
  __syncthreads();
  return r;
}
__device__ __forceinline__ float red128_sum(float v, int tid, float* red2) {
#pragma unroll
  for (int m = 32; m > 0; m >>= 1) v += __shfl_xor(v, m);
  if (tid == 0) red2[0] = v;
  if (tid == 64) red2[1] = v;
  __syncthreads();
  float r = red2[0] + red2[1];
  __syncthreads();
  return r;
}

// ---------------------------------------------------------------- embedding
__global__ __launch_bounds__(256) void k_embed(const int* __restrict__ tok,
                                               const float* __restrict__ emb,
                                               float* __restrict__ x) {
  int gid = blockIdx.x * 256 + threadIdx.x;  // < B*T*E = 2097152
  int bt = gid >> 8, k = gid & 255;
  int t = tok[bt];
  x[gid] = tanhf(emb[(size_t)t * ED + k]);
}

// ------------------------------------------- one-time W_iface transpose
__global__ __launch_bounds__(256) void k_wift(const float* __restrict__ wif,
                                              float* __restrict__ wifT) {
  int gid = blockIdx.x * 256 + threadIdx.x;  // < 512*471 = 241152
  int k = gid / NIF, c = gid - k * NIF;
  wifT[(size_t)c * 512 + k] = wif[gid];
}

// ------------------------------------------------- LSTM gates + cell update
// 1024 threads: (kq 2b | jj 3b | b 5b). Block covers units [2bk, 2bk+2).
__global__ __launch_bounds__(1024) void k_gates(
    const float* __restrict__ xall, const float* __restrict__ rv,
    const float* __restrict__ h0, float* __restrict__ c,
    const float* __restrict__ wih, const float* __restrict__ whh,
    const float* __restrict__ blstm, float* __restrict__ hrv, int step) {
  __shared__ float U[NB][257];     // +1 pad
  __shared__ float Gp[4][8][33];   // partial gates per kq
  const int tid = threadIdx.x;
  const int b = tid & 31, jj = (tid >> 5) & 7, kq = tid >> 8;
  const int ul = jj >> 2, g = jj & 3;
  const int u0 = blockIdx.x * 2;
  const int j = (u0 + ul) + (g << 9);  // gate row in [0,2048)
  float a0 = 0.f, a1 = 0.f, a2 = 0.f, a3 = 0.f;
  const float* wbase = wih + (size_t)j * 512;
  const float* wbase2 = whh + (size_t)j * 512;
  for (int tile = 0; tile < 4; ++tile) {
#pragma unroll
    for (int i = 0; i < 2; ++i) {
      int f = tid + (i << 10);
      int bb = f >> 6, k = (f & 63) << 2;
      const float* src;
      if (tile == 0)
        src = xall + (((size_t)bb * TB + step) << 8) + k;
      else if (tile == 1)
        src = rv + (bb << 8) + k;
      else {
        const float* hp = step ? (hrv + ((size_t)bb * TB + step - 1) * 768)
                               : (h0 + (bb << 9));
        src = hp + ((tile - 2) << 8) + k;
      }
      float4 v = *reinterpret_cast<const float4*>(src);
      U[bb][k] = v.x; U[bb][k + 1] = v.y; U[bb][k + 2] = v.z; U[bb][k + 3] = v.w;
    }
    __syncthreads();
    const float4* wp = reinterpret_cast<const float4*>(
        (tile < 2 ? wbase : wbase2) + ((tile & 1) << 8) + (kq << 6));
    const int kb = kq << 6;
#pragma unroll 4
    for (int k4 = 0; k4 < 16; ++k4) {
      float4 w4 = wp[k4];
      int k = kb + (k4 << 2);
      a0 = fmaf(U[b][k], w4.x, a0);
      a1 = fmaf(U[b][k + 1], w4.y, a1);
      a2 = fmaf(U[b][k + 2], w4.z, a2);
      a3 = fmaf(U[b][k + 3], w4.w, a3);
    }
    __syncthreads();
  }
  Gp[kq][jj][b] = (a0 + a1) + (a2 + a3);
  __syncthreads();
  if (tid < 64) {
    int u2 = tid >> 5, bb = tid & 31;
    int u = u0 + u2;
    float gv[4];
#pragma unroll
    for (int g2 = 0; g2 < 4; ++g2) {
      int jj2 = u2 * 4 + g2;
      gv[g2] = blstm[u + (g2 << 9)] + Gp[0][jj2][bb] + Gp[1][jj2][bb] +
               Gp[2][jj2][bb] + Gp[3][jj2][bb];
    }
    float cold = c[(bb << 9) + u];
    float cn = sigm(gv[1]) * cold + sigm(gv[0]) * tanhf(gv[2]);
    float hn = sigm(gv[3]) * tanhf(cn);
    c[(bb << 9) + u] = cn;
    hrv[((size_t)bb * TB + step) * 768 + u] = hn;
  }
}

// ------------------------------------------------ batched interface matvec
// xi[b][c] = h[b] . W_iface[:,c] + b_iface[c]. Block = 2 cols x 32 batches.
// Threads: (kq 2b | cl 1b | b 5b). Weights read once per step (wifT rows).
__global__ __launch_bounds__(256) void k_iface(
    const float* __restrict__ hrv, const float* __restrict__ wifT,
    const float* __restrict__ bif, float* __restrict__ xi_g, int step) {
  __shared__ float xp[4][2][33];
  const int tid = threadIdx.x;
  const int b = tid & 31, cl = (tid >> 5) & 1, kq = tid >> 6;
  const int c = blockIdx.x * 2 + cl;
  float a0 = 0.f, a1 = 0.f, a2 = 0.f, a3 = 0.f;
  if (c < NIF) {
    const float4* hp4 = reinterpret_cast<const float4*>(
        hrv + ((size_t)b * TB + step) * 768 + (kq << 7));
    const float4* wp4 =
        reinterpret_cast<const float4*>(wifT + (size_t)c * 512 + (kq << 7));
#pragma unroll 4
    for (int k4 = 0; k4 < 32; ++k4) {
      float4 h4 = hp4[k4];
      float4 w4 = wp4[k4];
      a0 = fmaf(h4.x, w4.x, a0);
      a1 = fmaf(h4.y, w4.y, a1);
      a2 = fmaf(h4.z, w4.z, a2);
      a3 = fmaf(h4.w, w4.w, a3);
    }
  }
  xp[kq][cl][b] = (a0 + a1) + (a2 + a3);
  __syncthreads();
  if (tid < 64) {
    int bb = tid & 31, cl2 = tid >> 5;
    int c2 = blockIdx.x * 2 + cl2;
    if (c2 < NIF) {
      float v = bif[c2] + xp[0][cl2][bb] + xp[1][cl2][bb] + xp[2][cl2][bb] +
                xp[3][cl2][bb];
      xi_g[bb * NIFP + c2] = v;
    }
  }
}

// --------------------------------------- DNC memory step (one block/batch)
// 1024 threads. M and L both live in (dynamic) LDS. L XOR-swizzled so both
// row-wise float4 reads (fwd) and column-wise scalar reads (bwd) are
// conflict-free. xi precomputed by k_iface.
#define MS(n, w) Ms[(n) * 65 + (w)]
#define LIDX(n, m) (((n) << 7) + ((m) ^ (((n)&7) << 2)))

__global__ __launch_bounds__(1024) void k_mem(
    float* __restrict__ hrv, const float* __restrict__ xi_g,
    float* __restrict__ M_g, float* __restrict__ L_g, float* __restrict__ p_g,
    float* __restrict__ u_g, float* __restrict__ wr_g,
    float* __restrict__ ww_g, float* __restrict__ rv_g, int step) {
  extern __shared__ float dyn[];
  float* Ls = dyn;            // 128*128 swizzled
  float* Ms = dyn + 16384;    // 128*65 (+1 pad)

  __shared__ float xi_s[472];
  __shared__ float wro_s[4][NM];
  __shared__ float fwd_s[4][NM];
  __shared__ float bwd_s[4][NM];
  __shared__ float crsd_s[4][NM];
  __shared__ float wrn_s[4][NM];
  __shared__ float fwdp[4][4][NM];  // [q][r][n]
  __shared__ float bwdp[4][4][NM];
  __shared__ float un_s[NM];
  __shared__ float wwn_s[NM];
  __shared__ float po_s[NM];
  __shared__ float nrmp_s[NM][8];
  __shared__ float nrm_s[NM];
  __shared__ float er_s[WDIM];
  __shared__ float wv_s[WDIM];
  __shared__ float rvp_s[256][5];
  __shared__ float rb_s[4], fg_s[4], rkn_s[4];
  __shared__ float pi_s[12];
  __shared__ float red2[2];
  __shared__ float redw[8];
  __shared__ float hm_s[4], hs_s[4];
  __shared__ float sc_s[4];  // 0: wb, 1: ga, 2: gw, 3: |wk|

  const int tid = threadIdx.x;
  const int b = blockIdx.x;
  const size_t row = (size_t)b * TB + step;
  float* hp = hrv + row * 768;
  float* Mg = M_g + (size_t)b * (NM * WDIM);
  float* Lg = L_g + (size_t)b * (NM * NM);

  // ---- phase A: fills
  for (int f = tid; f < 2048; f += 1024) {
    float4 v = reinterpret_cast<const float4*>(Mg)[f];
    int n = f >> 4, w = (f & 15) << 2;
    MS(n, w) = v.x; MS(n, w + 1) = v.y; MS(n, w + 2) = v.z; MS(n, w + 3) = v.w;
  }
  for (int f = tid; f < 4096; f += 1024) {
    float4 v = reinterpret_cast<const float4*>(Lg)[f];
    int n = f >> 5, m = (f & 31) << 2;
    *reinterpret_cast<float4*>(&Ls[LIDX(n, m)]) = v;
  }
  if (tid < 512) wro_s[tid >> 7][tid & 127] = wr_g[b * 512 + tid];
  float uo = 0.f, wwo = 0.f;
  if (tid < 128) {
    uo = u_g[b * 128 + tid];
    wwo = ww_g[b * 128 + tid];
    po_s[tid] = p_g[b * 128 + tid];
  }
  if (tid < NIF) xi_s[tid] = xi_g[b * NIFP + tid];
  __syncthreads();

  // ---- parse interface
  if (tid < 64) {
    er_s[tid] = sigm(xi_s[325 + tid]);
    wv_s[tid] = xi_s[389 + tid];
  } else if (tid < 68) {
    rb_s[tid - 64] = 1.0f + sofp(xi_s[256 + (tid - 64)]);
  } else if (tid < 72) {
    fg_s[tid - 68] = sigm(xi_s[453 + (tid - 68)]);
  } else if (tid < 76) {
    int r = tid - 72;
    float nq = 0.f;
    for (int w = 0; w < 64; ++w) { float v = xi_s[r * 64 + w]; nq = fmaf(v, v, nq); }
    rkn_s[r] = sqrtf(nq);
  } else if (tid < 80) {
    int r = tid - 76;
    float e0 = xi_s[459 + 3 * r], e1 = xi_s[460 + 3 * r], e2 = xi_s[461 + 3 * r];
    float mx = fmaxf(e0, fmaxf(e1, e2));
    float p0 = expf(e0 - mx), p1 = expf(e1 - mx), p2 = expf(e2 - mx);
    float s = p0 + p1 + p2;
    pi_s[3 * r] = p0 / s; pi_s[3 * r + 1] = p1 / s; pi_s[3 * r + 2] = p2 / s;
  } else if (tid == 80) {
    sc_s[0] = 1.0f + sofp(xi_s[324]);
  } else if (tid == 81) {
    sc_s[1] = sigm(xi_s[457]);
  } else if (tid == 82) {
    sc_s[2] = sigm(xi_s[458]);
  } else if (tid == 83) {
    float nq = 0.f;
    for (int w = 0; w < 64; ++w) { float v = xi_s[260 + w]; nq = fmaf(v, v, nq); }
    sc_s[3] = sqrtf(nq);
  }
  __syncthreads();

  // ---- B1: retention/usage + content-write scores (old M)
  float score = -1e30f;
  if (tid < 128) {
    int n = tid;
    float psi = 1.0f;
#pragma unroll
    for (int r = 0; r < 4; ++r) psi *= (1.0f - fg_s[r] * wro_s[r][n]);
    float un = (uo + wwo - uo * wwo) * psi;
    un_s[n] = un;
    u_g[b * 128 + n] = un;
    float d0 = 0.f, d1 = 0.f, q0 = 0.f, q1 = 0.f;
#pragma unroll 4
    for (int w = 0; w < 64; w += 2) {
      float m0 = MS(n, w), m1 = MS(n, w + 1);
      d0 = fmaf(m0, xi_s[260 + w], d0); q0 = fmaf(m0, m0, q0);
      d1 = fmaf(m1, xi_s[260 + w + 1], d1); q1 = fmaf(m1, m1, q1);
    }
    score = sc_s[0] * (d0 + d1) / (sc_s[3] * sqrtf(q0 + q1) + CEPS);
  }
  __syncthreads();

  // ---- B2: allocation (stable-order O(N^2) product == stable argsort+cumprod)
  float aval = 0.f;
  if (tid < 128) {
    int n = tid;
    float un = un_s[n];
    float p0 = 1.0f, p1 = 1.0f;
#pragma unroll 4
    for (int m = 0; m < 128; m += 2) {
      float u0 = un_s[m], u1 = un_s[m + 1];
      p0 *= ((u0 < un) || (u0 == un && m < n)) ? u0 : 1.0f;
      p1 *= ((u1 < un) || (u1 == un && (m + 1) < n)) ? u1 : 1.0f;
    }
    aval = (1.0f - un) * p0 * p1;
  }
  float gmax = red128_max(score, tid, red2);
  float ev = (tid < 128) ? expf(score - gmax) : 0.f;
  float gsum = red128_sum(ev, tid, red2);
  float wwv = 0.f;
  if (tid < 128) {
    float cw = ev / gsum;
    wwv = sc_s[2] * (sc_s[1] * aval + (1.0f - sc_s[1]) * cw);
    wwn_s[tid] = wwv;
    ww_g[b * 128 + tid] = wwv;
  }
  float sumww = red128_sum(wwv, tid, red2);  // syncs make wwn_s visible

  // ---- B3: M update (+norm partials), L update (LDS + writeback), p update
  {
    int n = tid >> 3, w0 = (tid & 7) << 3;
    float wn = wwn_s[n];
    float nq = 0.f;
    float mv_[8];
#pragma unroll
    for (int jx = 0; jx < 8; ++jx) {
      int w = w0 + jx;
      float mv = MS(n, w);
      mv = mv * (1.0f - wn * er_s[w]) + wn * wv_s[w];
      MS(n, w) = mv;
      mv_[jx] = mv;
      nq = fmaf(mv, mv, nq);
    }
    nrmp_s[n][tid & 7] = nq;
    float4* mg4 = reinterpret_cast<float4*>(Mg + (n << 6) + w0);
    mg4[0] = make_float4(mv_[0], mv_[1], mv_[2], mv_[3]);
    mg4[1] = make_float4(mv_[4], mv_[5], mv_[6], mv_[7]);
  }
  for (int f = tid; f < 4096; f += 1024) {
    int n = f >> 5, m = (f & 31) << 2;
    float4* lp = reinterpret_cast<float4*>(&Ls[LIDX(n, m)]);
    float4 lv = *lp;
    float wn = wwn_s[n];
    float4 nv;
    nv.x = (n == m + 0) ? 0.f : (1.f - wn - wwn_s[m + 0]) * lv.x + wn * po_s[m + 0];
    nv.y = (n == m + 1) ? 0.f : (1.f - wn - wwn_s[m + 1]) * lv.y + wn * po_s[m + 1];
    nv.z = (n == m + 2) ? 0.f : (1.f - wn - wwn_s[m + 2]) * lv.z + wn * po_s[m + 2];
    nv.w = (n == m + 3) ? 0.f : (1.f - wn - wwn_s[m + 3]) * lv.w + wn * po_s[m + 3];
    *lp = nv;
    reinterpret_cast<float4*>(Lg)[f] = nv;
  }
  if (tid < 128) p_g[b * 128 + tid] = (1.0f - sumww) * po_s[tid] + wwn_s[tid];
  __syncthreads();

  // ---- B4: fwd/bwd partials (m-split, heads inner, L read once per type)
  //          || cr raw dots (new M)
  if (tid < 512) {
    int q = tid >> 7, n = tid & 127;
    int m0 = q << 5;
    float f0 = 0, f1 = 0, f2 = 0, f3 = 0, g0 = 0, g1 = 0, g2 = 0, g3 = 0;
#pragma unroll
    for (int m = m0; m < m0 + 32; m += 4) {
      float4 l4 = *reinterpret_cast<const float4*>(&Ls[LIDX(n, m)]);
      f0 = fmaf(l4.x, wro_s[0][m], f0);     f0 = fmaf(l4.y, wro_s[0][m + 1], f0);
      f0 = fmaf(l4.z, wro_s[0][m + 2], f0); f0 = fmaf(l4.w, wro_s[0][m + 3], f0);
      f1 = fmaf(l4.x, wro_s[1][m], f1);     f1 = fmaf(l4.y, wro_s[1][m + 1], f1);
      f1 = fmaf(l4.z, wro_s[1][m + 2], f1); f1 = fmaf(l4.w, wro_s[1][m + 3], f1);
      f2 = fmaf(l4.x, wro_s[2][m], f2);     f2 = fmaf(l4.y, wro_s[2][m + 1], f2);
      f2 = fmaf(l4.z, wro_s[2][m + 2], f2); f2 = fmaf(l4.w, wro_s[2][m + 3], f2);
      f3 = fmaf(l4.x, wro_s[3][m], f3);     f3 = fmaf(l4.y, wro_s[3][m + 1], f3);
      f3 = fmaf(l4.z, wro_s[3][m + 2], f3); f3 = fmaf(l4.w, wro_s[3][m + 3], f3);
    }
#pragma unroll 4
    for (int m = m0; m < m0 + 32; ++m) {
      float lv = Ls[LIDX(m, n)];
      g0 = fmaf(lv, wro_s[0][m], g0);
      g1 = fmaf(lv, wro_s[1][m], g1);
      g2 = fmaf(lv, wro_s[2][m], g2);
      g3 = fmaf(lv, wro_s[3][m], g3);
    }
    fwdp[q][0][n] = f0; fwdp[q][1][n] = f1; fwdp[q][2][n] = f2; fwdp[q][3][n] = f3;
    bwdp[q][0][n] = g0; bwdp[q][1][n] = g1; bwdp[q][2][n] = g2; bwdp[q][3][n] = g3;
  } else {
    int s = tid - 512;
    int r = s >> 7, n = s & 127;
    const float* xk = xi_s + r * 64;
    float d0 = 0.f, d1 = 0.f, d2 = 0.f, d3 = 0.f;
#pragma unroll 4
    for (int w = 0; w < 64; w += 4) {
      d0 = fmaf(MS(n, w + 0), xk[w + 0], d0);
      d1 = fmaf(MS(n, w + 1), xk[w + 1], d1);
      d2 = fmaf(MS(n, w + 2), xk[w + 2], d2);
      d3 = fmaf(MS(n, w + 3), xk[w + 3], d3);
    }
    crsd_s[r][n] = (d0 + d1) + (d2 + d3);
  }
  __syncthreads();
  // combine partials + M row norms
  {
    int r = (tid >> 7) & 3, n = tid & 127;
    if (tid < 512) {
      fwd_s[r][n] = fwdp[0][r][n] + fwdp[1][r][n] + fwdp[2][r][n] + fwdp[3][r][n];
      if (tid < 128) {
        float s = 0.f;
#pragma unroll
        for (int jx = 0; jx < 8; ++jx) s += nrmp_s[tid][jx];
        nrm_s[tid] = sqrtf(s);
      }
    } else {
      bwd_s[r][n] = bwdp[0][r][n] + bwdp[1][r][n] + bwdp[2][r][n] + bwdp[3][r][n];
    }
  }
  __syncthreads();

  // ---- B5: batched 4-head softmax over slots, then read weights
  {
    int r = (tid >> 7) & 3, n = tid & 127;
    float v = -1e30f;
    if (tid < 512) v = rb_s[r] * crsd_s[r][n] / (rkn_s[r] * nrm_s[n] + CEPS);
    float mx = v;
#pragma unroll
    for (int m = 32; m > 0; m >>= 1) mx = fmaxf(mx, __shfl_xor(mx, m));
    if ((tid & 63) == 0 && tid < 512) redw[tid >> 6] = mx;
    __syncthreads();
    if (tid < 4) hm_s[tid] = fmaxf(redw[2 * tid], redw[2 * tid + 1]);
    __syncthreads();
    float e = 0.f;
    if (tid < 512) e = expf(v - hm_s[r]);
    float sm = e;
#pragma unroll
    for (int m = 32; m > 0; m >>= 1) sm += __shfl_xor(sm, m);
    if ((tid & 63) == 0 && tid < 512) redw[tid >> 6] = sm;
    __syncthreads();
    if (tid < 4) hs_s[tid] = redw[2 * tid] + redw[2 * tid + 1];
    __syncthreads();
    if (tid < 512) {
      float crn = e / hs_s[r];
      float w = pi_s[3 * r] * bwd_s[r][n] + pi_s[3 * r + 1] * crn +
                pi_s[3 * r + 2] * fwd_s[r][n];
      wrn_s[r][n] = w;
      wr_g[b * 512 + r * 128 + n] = w;
    }
  }
  __syncthreads();

  // ---- B6: read vectors rv = wr_new @ M_new ; 4 threads per output
  {
    int out = tid & 255, q = tid >> 8;
    int r = out >> 6, w = out & 63;
    const float* wrr = wrn_s[r];
    int n0 = q << 5;
    float a0 = 0.f, a1 = 0.f;
#pragma unroll 4
    for (int n = n0; n < n0 + 32; n += 2) {
      a0 = fmaf(wrr[n], MS(n, w), a0);
      a1 = fmaf(wrr[n + 1], MS(n + 1, w), a1);
    }
    rvp_s[out][q] = a0 + a1;
  }
  __syncthreads();
  if (tid < 256) {
    float acc = rvp_s[tid][0] + rvp_s[tid][1] + rvp_s[tid][2] + rvp_s[tid][3];
    rv_g[b * 256 + tid] = acc;
    hp[512 + tid] = acc;
  }
}

// ---------------------------------------------- deferred output projection
// C(8192x10000) = A(8192x768) @ W(768x10000) + bias ; fp32, 128x128x8 tiles.
__global__ __launch_bounds__(256) void k_out(const float* __restrict__ A,
                                             const float* __restrict__ W,
                                             const float* __restrict__ bias,
                                             float* __restrict__ C) {
  __shared__ float As[8][128];
  __shared__ float Bs[8][128];
  const int tid = threadIdx.x;
  const int tx = tid & 15, ty = tid >> 4;
  const int m0 = blockIdx.x << 7;
  const int n0 = blockIdx.y << 7;
  float acc[8][8];
#pragma unroll
  for (int i = 0; i < 8; ++i)
#pragma unroll
    for (int j = 0; j < 8; ++j) acc[i][j] = 0.f;
  const int arow = tid >> 1, akk = (tid & 1) << 2;
  const int bk = tid >> 5, bn = (tid & 31) << 2;
  for (int k0 = 0; k0 < 768; k0 += 8) {
    float4 av = *reinterpret_cast<const float4*>(A + (size_t)(m0 + arow) * 768 + k0 + akk);
    float4 bv = make_float4(0.f, 0.f, 0.f, 0.f);
    if (n0 + bn < EV)
      bv = *reinterpret_cast<const float4*>(W + (size_t)(k0 + bk) * EV + n0 + bn);
    __syncthreads();  // previous iteration's reads complete
    As[akk + 0][arow] = av.x; As[akk + 1][arow] = av.y;
    As[akk + 2][arow] = av.z; As[akk + 3][arow] = av.w;
    *reinterpret_cast<float4*>(&Bs[bk][bn]) = bv;
    __syncthreads();
#pragma unroll
    for (int k = 0; k < 8; ++k) {
      float a_[8], b_[8];
#pragma unroll
      for (int i = 0; i < 8; ++i) a_[i] = As[k][ty + (i << 4)];
#pragma unroll
      for (int j = 0; j < 8; ++j) b_[j] = Bs[k][tx + (j << 4)];
#pragma unroll
      for (int i = 0; i < 8; ++i)
#pragma unroll
        for (int j = 0; j < 8; ++j) acc[i][j] = fmaf(a_[i], b_[j], acc[i][j]);
    }
  }
#pragma unroll
  for (int i = 0; i < 8; ++i) {
    int row = m0 + ty + (i << 4);
#pragma unroll
    for (int j = 0; j < 8; ++j) {
      int col = n0 + tx + (j << 4);
      if (col < EV) C[(size_t)row * EV + col] = acc[i][j] + bias[col];
    }
  }
}

extern "C" void kernel_launch(void* const* d_in, const int* in_sizes, int n_in,
                              void* d_out, int out_size, void* d_ws,
                              size_t ws_size, hipStream_t stream) {
  const int* tokens = (const int*)d_in[0];
  const float* emb = (const float*)d_in[1];
  const float* wih = (const float*)d_in[2];
  const float* whh = (const float*)d_in[3];
  const float* blstm = (const float*)d_in[4];
  const float* wif = (const float*)d_in[5];
  const float* bif = (const float*)d_in[6];
  const float* wout = (const float*)d_in[7];
  const float* bout = (const float*)d_in[8];
  float* out = (float*)d_out;

  float* ws = (float*)d_ws;
  float* xall = ws;                    // 2,097,152
  float* hrv = xall + 2097152;         // 6,291,456  (B*T x [h(512)|rv(256)])
  float* h0 = hrv + 6291456;           // state block start (zeroed)
  float* cS = h0 + 16384;
  float* MS_ = cS + 16384;
  float* LS_ = MS_ + 262144;
  float* pS = LS_ + 524288;
  float* uS = pS + 4096;
  float* wrS = uS + 4096;
  float* wwS = wrS + 16384;
  float* rvS = wwS + 4096;             // state ends at h0 + 856064
  float* xiS = h0 + 856064;            // 32*480 = 15,360
  float* wifT = xiS + 15360;           // 471*512 -> 241,152

  static bool attr_set = false;
  if (!attr_set) {
    hipFuncSetAttribute(reinterpret_cast<const void*>(k_mem),
                        hipFuncAttributeMaxDynamicSharedMemorySize, 98816);
    attr_set = true;
  }

  hipMemsetAsync(h0, 0, (size_t)856064 * sizeof(float), stream);
  k_wift<<<942, 256, 0, stream>>>(wif, wifT);
  k_embed<<<8192, 256, 0, stream>>>(tokens, emb, xall);
  for (int t = 0; t < TB; ++t) {
    k_gates<<<256, 1024, 0, stream>>>(xall, rvS, h0, cS, wih, whh, blstm, hrv, t);
    k_iface<<<236, 256, 0, stream>>>(hrv, wifT, bif, xiS, t);
    k_mem<<<32, 1024, 98816, stream>>>(hrv, xiS, MS_, LS_, pS, uS, wrS, wwS,
                                       rvS, t);
  }
  dim3 g(64, 79);
  k_out<<<g, 256, 0, stream>>>(hrv, wout, bout, out);
}